// Round 5
// baseline (125.736 us; speedup 1.0000x reference)
//
#include <hip/hip_runtime.h>

// Levenshtein edit distance, ref (512,B) x hyp (512,B), B=1024, unit costs.
// Anti-diagonal wavefront, one 64-lane wave per problem, 8 cells/lane packed
// 2-per-register in PARITY-STRIDED layout: reg p = cells {p, p+4} (lo,hi).
//
// r12: TWO-STEP FUSED mega-asm. r11 post-mortem: busy cyc/step matches the
// 28-instr hand count exactly at any consistent clock; ~27 ns/step idle
// remains, located at the per-step block boundaries (builtin DPPs between
// opaque asm blocks; their results consumed 1-4 instrs later, their sources
// produced <=3 instrs before block end, s_nop hazards + dep bubbles at the
// seams). Step N+1 has ~12 ops independent of step N's tail (xors of old
// queue regs, token-DPP, min(x,1) chain) — only a fused asm block can
// interleave them. This block:
//  - raw v_mov_b32_dpp wave_shr:1 (gfx9 syntax, bound_ctrl omitted = old
//    preserved on lane 0 — same semantics as the r3-r7-verified builtin);
//  - every VALU-write -> DPP-src-read distance >=3 instructions (HW needs 2);
//  - every dependent pair >=3 instructions apart (>=6 cyc);
//  - values feeding the NEXT block's DPPs (P3, hne) produced >=3 instrs
//    before block end.
// Same 28 VALU/step — pure stall-elimination experiment.
//
// Biased relative domain (exact, r7-verified): w = v - d + 1024 in [0,1024].
//   AN = min(a1s, A1, a2s + nq - 2),  nq = (ref!=hyp) via min_u16(xor,1)
// i=0 boundary: constant 1024 via persistent vseam lane0. j=0 boundary:
// fake-init 0x3FFF (decays <=2/step -> >=14337 at end, never beats real).
// nq-2 added as 0xFFFE per lane (mod-2^16 exact; true result >= 0).
// Token loads exist only for d<=517 (injections at d>=514 provably cannot
// reach the answer cell); second half of the kernel is load-free.

#define HLEN 512
#define BATCH 1024
#define FAKE2  0x3FFF3FFFu  // packed fake-infinity
#define SENT2  0x03FF03FFu  // packed token sentinel (real tokens < 1000)
#define BIASHI 0x04000000u  // 1024 in high half: persistent lane0 of vseam
#define ONE2   0x00010001u
#define NEG22  0xFFFEFFFEu  // -2 per 16-bit lane

// lane L gets src from lane L-1; lane 0 KEEPS OLD DEST (gfx9 DPP WAVE_SHR1,
// bound_ctrl=false, old operand tied to dest). HW-verified rounds 3-7.
__device__ __forceinline__ unsigned upd_dpp(unsigned old, unsigned src) {
  return (unsigned)__builtin_amdgcn_update_dpp((int)old, (int)src, 0x138, 0xF, 0xF, false);
}

// ---- Fused double step ----------------------------------------------------
// Roles: first (even) step: A2=P, A1=Q, AN=R; second (odd) step: A2=Q,
// A1=R, AN=P. Queue args (QA,QB,QC,QD): even step = (QA,QB,QC,QD) writes
// QD:=hne; odd step = (QD,QA,QB,QC) writes QC:=hno. T0v/T1v: token regs
// (bits[31:16] = token, d16_hi load dest), consumed in place as dpp old.
// Schedule: breadth-first across both steps; dep gaps >=3 instrs; DPP
// hazard (VALU-write->dpp-src) gaps >=3; P3/hne for next block's DPPs
// produced early enough. s0c in: prev a1s0; out: odd step's a1s0.
#define STEP2(P, Q, R, QA, QB, QC, QD, T0v, T1v)                        \
  do {                                                                  \
    unsigned c0e_, c1e_, c2e_, c3e_, c0o_, c1o_, c2o_, c3o_;            \
    unsigned hne_, hno_, a1e_, a1o_;                                    \
    asm("v_mov_b32_dpp %[T0], %[qd] wave_shr:1 row_mask:0xf bank_mask:0xf\n\t" \
        "v_mov_b32_dpp %[vs], %[Q3] wave_shr:1 row_mask:0xf bank_mask:0xf\n\t" \
        "v_xor_b32 %[c2o], %[rt2], %[qa]\n\t"                           \
        "v_xor_b32 %[c3o], %[rt3], %[qb]\n\t"                           \
        "v_alignbit_b32 %[hne], %[qd], %[T0], 16\n\t"                   \
        "v_alignbit_b32 %[a1e], %[Q3], %[vs], 16\n\t"                   \
        "v_xor_b32 %[c1e], %[rt1], %[qa]\n\t"                           \
        "v_xor_b32 %[c2e], %[rt2], %[qb]\n\t"                           \
        "v_xor_b32 %[c3e], %[rt3], %[qc]\n\t"                           \
        "v_xor_b32 %[c0e], %[rt0], %[hne]\n\t"                          \
        "v_pk_min_u16 %[c1e], %[c1e], %[one]\n\t"                       \
        "v_pk_min_u16 %[c2e], %[c2e], %[one]\n\t"                       \
        "v_pk_min_u16 %[c3e], %[c3e], %[one]\n\t"                       \
        "v_pk_min_u16 %[c0e], %[c0e], %[one]\n\t"                       \
        "v_pk_add_u16 %[c1e], %[c1e], %[neg2]\n\t"                      \
        "v_pk_add_u16 %[c2e], %[c2e], %[neg2]\n\t"                      \
        "v_pk_add_u16 %[c3e], %[c3e], %[neg2]\n\t"                      \
        "v_pk_add_u16 %[c0e], %[c0e], %[neg2]\n\t"                      \
        "v_pk_add_u16 %[c1e], %[c1e], %[P0]\n\t"                        \
        "v_pk_add_u16 %[c2e], %[c2e], %[P1]\n\t"                        \
        "v_pk_add_u16 %[c3e], %[c3e], %[P2]\n\t"                        \
        "v_pk_add_u16 %[c0e], %[c0e], %[s0c]\n\t"                       \
        "v_pk_min_u16 %[R1], %[Q0], %[Q1]\n\t"                          \
        "v_pk_min_u16 %[R2], %[Q1], %[Q2]\n\t"                          \
        "v_pk_min_u16 %[R3], %[Q2], %[Q3]\n\t"                          \
        "v_pk_min_u16 %[R0], %[a1e], %[Q0]\n\t"                         \
        "v_pk_min_u16 %[R1], %[R1], %[c1e]\n\t"                         \
        "v_pk_min_u16 %[R2], %[R2], %[c2e]\n\t"                         \
        "v_pk_min_u16 %[R3], %[R3], %[c3e]\n\t"                         \
        "v_pk_min_u16 %[R0], %[R0], %[c0e]\n\t"                         \
        "v_mov_b32_dpp %[T1], %[qc] wave_shr:1 row_mask:0xf bank_mask:0xf\n\t" \
        "v_xor_b32 %[c1o], %[rt1], %[hne]\n\t"                          \
        "v_mov_b32_dpp %[vs], %[R3] wave_shr:1 row_mask:0xf bank_mask:0xf\n\t" \
        "v_alignbit_b32 %[hno], %[qc], %[T1], 16\n\t"                   \
        "v_pk_min_u16 %[c2o], %[c2o], %[one]\n\t"                       \
        "v_pk_min_u16 %[c3o], %[c3o], %[one]\n\t"                       \
        "v_alignbit_b32 %[a1o], %[R3], %[vs], 16\n\t"                   \
        "v_xor_b32 %[c0o], %[rt0], %[hno]\n\t"                          \
        "v_pk_min_u16 %[c1o], %[c1o], %[one]\n\t"                       \
        "v_pk_add_u16 %[c2o], %[c2o], %[neg2]\n\t"                      \
        "v_pk_add_u16 %[c3o], %[c3o], %[neg2]\n\t"                      \
        "v_pk_min_u16 %[c0o], %[c0o], %[one]\n\t"                       \
        "v_pk_add_u16 %[c1o], %[c1o], %[neg2]\n\t"                      \
        "v_pk_add_u16 %[c2o], %[c2o], %[Q1]\n\t"                        \
        "v_pk_add_u16 %[c3o], %[c3o], %[Q2]\n\t"                        \
        "v_pk_add_u16 %[c0o], %[c0o], %[neg2]\n\t"                      \
        "v_pk_add_u16 %[c1o], %[c1o], %[Q0]\n\t"                        \
        "v_pk_min_u16 %[P1], %[R0], %[R1]\n\t"                          \
        "v_pk_min_u16 %[P2], %[R1], %[R2]\n\t"                          \
        "v_pk_add_u16 %[c0o], %[c0o], %[a1e]\n\t"                       \
        "v_pk_min_u16 %[P3], %[R2], %[R3]\n\t"                          \
        "v_pk_min_u16 %[P0], %[a1o], %[R0]\n\t"                         \
        "v_pk_min_u16 %[P1], %[P1], %[c1o]\n\t"                         \
        "v_pk_min_u16 %[P3], %[P3], %[c3o]\n\t"                         \
        "v_pk_min_u16 %[P2], %[P2], %[c2o]\n\t"                         \
        "v_pk_min_u16 %[P0], %[P0], %[c0o]\n\t"                         \
        : [R0]"=&v"(R[0]), [R1]"=&v"(R[1]), [R2]"=&v"(R[2]), [R3]"=&v"(R[3]), \
          [P0]"+v"(P[0]), [P1]"+v"(P[1]), [P2]"+v"(P[2]), [P3]"+v"(P[3]), \
          [T0]"+v"(T0v), [T1]"+v"(T1v), [vs]"+v"(vseam),                \
          [hne]"=&v"(hne_), [hno]"=&v"(hno_),                           \
          [a1e]"=&v"(a1e_), [a1o]"=&v"(a1o_),                           \
          [c0e]"=&v"(c0e_), [c1e]"=&v"(c1e_), [c2e]"=&v"(c2e_), [c3e]"=&v"(c3e_), \
          [c0o]"=&v"(c0o_), [c1o]"=&v"(c1o_), [c2o]"=&v"(c2o_), [c3o]"=&v"(c3o_)  \
        : [Q0]"v"(Q[0]), [Q1]"v"(Q[1]), [Q2]"v"(Q[2]), [Q3]"v"(Q[3]),   \
          [qa]"v"(QA), [qb]"v"(QB), [qc]"v"(QC), [qd]"v"(QD),           \
          [rt0]"v"(rt[0]), [rt1]"v"(rt[1]), [rt2]"v"(rt[2]), [rt3]"v"(rt[3]), \
          [one]"v"(one2), [neg2]"v"(neg2), [s0c]"v"(s0c));              \
    QD = hne_; QC = hno_; s0c = a1o_;                                   \
  } while (0)

// Single step (r11 form) — used once in the epilogue only.
#define STEP1(A2, A1, AN, Q0, Q1, Q2, Q3, TREG)                         \
  do {                                                                  \
    unsigned t0, t1, t2, t3, m0, m1, m2, m3, a1s0, hn;                  \
    vseam = upd_dpp(vseam, A1[3]);                                      \
    TREG = upd_dpp(TREG, Q3);                                           \
    asm("v_xor_b32 %[t1], %[rt1], %[q0]\n\t"                            \
        "v_xor_b32 %[t2], %[rt2], %[q1]\n\t"                            \
        "v_xor_b32 %[t3], %[rt3], %[q2]\n\t"                            \
        "v_alignbit_b32 %[a1s0], %[a13], %[vs], 16\n\t"                 \
        "v_alignbit_b32 %[hn], %[q3], %[tq], 16\n\t"                    \
        : [t1]"=&v"(t1), [t2]"=&v"(t2), [t3]"=&v"(t3),                  \
          [a1s0]"=&v"(a1s0), [hn]"=&v"(hn)                              \
        : [rt1]"v"(rt[1]), [rt2]"v"(rt[2]), [rt3]"v"(rt[3]),            \
          [q0]"v"(Q0), [q1]"v"(Q1), [q2]"v"(Q2), [q3]"v"(Q3),           \
          [a13]"v"(A1[3]), [vs]"v"(vseam), [tq]"v"(TREG));              \
    asm("v_pk_min_u16 %[t1], %[t1], %[one]\n\t"                         \
        "v_pk_min_u16 %[t2], %[t2], %[one]\n\t"                         \
        "v_xor_b32    %[t0], %[rt0], %[hn]\n\t"                         \
        "v_pk_min_u16 %[t3], %[t3], %[one]\n\t"                         \
        "v_pk_add_u16 %[t1], %[t1], %[neg2]\n\t"                        \
        "v_pk_min_u16 %[t0], %[t0], %[one]\n\t"                         \
        "v_pk_add_u16 %[t2], %[t2], %[neg2]\n\t"                        \
        "v_pk_add_u16 %[t3], %[t3], %[neg2]\n\t"                        \
        "v_pk_add_u16 %[t1], %[t1], %[a20]\n\t"                         \
        "v_pk_add_u16 %[t0], %[t0], %[neg2]\n\t"                        \
        "v_pk_min_u16 %[m3], %[a12], %[a13]\n\t"                        \
        "v_pk_min_u16 %[m1], %[a10], %[a11]\n\t"                        \
        "v_pk_add_u16 %[t2], %[t2], %[a21]\n\t"                         \
        "v_pk_add_u16 %[t3], %[t3], %[a22]\n\t"                         \
        "v_pk_add_u16 %[t0], %[t0], %[s0c]\n\t"                         \
        "v_pk_min_u16 %[m2], %[a11], %[a12]\n\t"                        \
        "v_pk_min_u16 %[m0], %[a1s0], %[a10]\n\t"                       \
        "v_pk_min_u16 %[t3], %[m3], %[t3]\n\t"                          \
        "v_pk_min_u16 %[t1], %[m1], %[t1]\n\t"                          \
        "v_pk_min_u16 %[t2], %[m2], %[t2]\n\t"                          \
        "v_pk_min_u16 %[t0], %[m0], %[t0]\n\t"                          \
        : [t0]"=&v"(t0), [t1]"+v"(t1), [t2]"+v"(t2), [t3]"+v"(t3),      \
          [m0]"=&v"(m0), [m1]"=&v"(m1), [m2]"=&v"(m2), [m3]"=&v"(m3)    \
        : [hn]"v"(hn), [a1s0]"v"(a1s0),                                 \
          [a10]"v"(A1[0]), [a11]"v"(A1[1]), [a12]"v"(A1[2]),            \
          [a13]"v"(A1[3]),                                              \
          [a20]"v"(A2[0]), [a21]"v"(A2[1]), [a22]"v"(A2[2]),            \
          [rt0]"v"(rt[0]), [one]"v"(one2), [neg2]"v"(neg2),             \
          [s0c]"v"(s0c));                                               \
    AN[0] = t0; AN[1] = t1; AN[2] = t2; AN[3] = t3;                     \
    s0c = a1s0;                                                         \
    Q3 = hn;                                                            \
  } while (0)

// Broadcast token load into HIGH half of DST (low half garbage — discarded
// by the alignbit). Uniform SGPR-pair base advanced on the scalar pipe.
#define TLOAD(DST) do {                                                \
    asm volatile("global_load_short_d16_hi %0, %1, %2"                 \
                 : "+v"(DST) : "v"(vz), "s"(hb2));                     \
    hb2 += 2048; /* +4096 bytes, uniform -> s_add/s_addc */            \
  } while (0)
// Frozen variant: load without advancing (compile-time clamp to token 511).
#define TLOADF(DST) do {                                               \
    asm volatile("global_load_short_d16_hi %0, %1, %2"                 \
                 : "+v"(DST) : "v"(vz), "s"(hb2));                     \
  } while (0)

// Counted waits tied to the consumed bank (rule #18 hoist fence).
#define TWAIT12(T)                                                     \
  asm volatile("s_waitcnt vmcnt(12)"                                   \
               : "+v"(T[0]), "+v"(T[1]), "+v"(T[2]), "+v"(T[3]),       \
                 "+v"(T[4]), "+v"(T[5]), "+v"(T[6]), "+v"(T[7]),       \
                 "+v"(T[8]), "+v"(T[9]), "+v"(T[10]), "+v"(T[11]));
#define TWAIT0(T)                                                      \
  asm volatile("s_waitcnt vmcnt(0)"                                    \
               : "+v"(T[0]), "+v"(T[1]), "+v"(T[2]), "+v"(T[3]),       \
                 "+v"(T[4]), "+v"(T[5]), "+v"(T[6]), "+v"(T[7]),       \
                 "+v"(T[8]), "+v"(T[9]), "+v"(T[10]), "+v"(T[11]));

// 12 steps = 6 fused double-steps. Diag roles period 3, queue tuple
// period 2 (verified against the r11 12-step unrolled sequence).
#define STEPS12(T)                                                     \
    STEP2(A,  Bv, Cv, q0, q1, q2, q3, T[0],  T[1]);                    \
    STEP2(Cv, A,  Bv, q2, q3, q0, q1, T[2],  T[3]);                    \
    STEP2(Bv, Cv, A,  q0, q1, q2, q3, T[4],  T[5]);                    \
    STEP2(A,  Bv, Cv, q2, q3, q0, q1, T[6],  T[7]);                    \
    STEP2(Cv, A,  Bv, q0, q1, q2, q3, T[8],  T[9]);                    \
    STEP2(Bv, Cv, A,  q2, q3, q0, q1, T[10], T[11]);

__global__ void __launch_bounds__(64)
edit_distance_kernel(const int* __restrict__ ref,
                     const int* __restrict__ hyp,
                     float* __restrict__ out) {
  const int b = blockIdx.x;        // one wave (block of 64) per batch element
  const int lane = threadIdx.x;    // 0..63

  // Parity-packed static ref tokens: rt[p] = {cell lane*8+p, cell lane*8+p+4}.
  unsigned rt[4];
#pragma unroll
  for (int p = 0; p < 4; ++p) {
    unsigned lo = (unsigned)ref[(lane * 8 + p) * BATCH + b];
    unsigned hi = (unsigned)ref[(lane * 8 + p + 4) * BATCH + b];
    rt[p] = lo | (hi << 16);
  }

  // Uniform token pointer at this problem's column (token j's low 16 bits
  // live at byte j*4096 + b*4, little-endian). Advanced on the scalar pipe.
  const unsigned short* hb2 = (const unsigned short*)hyp + (unsigned)b * 2u;
  unsigned vz;
  asm("v_mov_b32 %0, 0" : "=v"(vz));  // constant-zero VGPR offset

  unsigned tA[12] = {0,0,0,0,0,0,0,0,0,0,0,0};
  unsigned tB[12] = {0,0,0,0,0,0,0,0,0,0,0,0};

  // Prologue prefetch: bank A = tokens 0-11 (iteration 0).
#pragma unroll
  for (int j = 0; j < 12; ++j) TLOAD(tA[j]);

  const unsigned one2 = ONE2;
  const unsigned neg2 = NEG22;

  // Rotating parity-packed diagonal buffers.
  unsigned A[4], Bv[4], Cv[4];
#pragma unroll
  for (int p = 0; p < 4; ++p) { A[p] = FAKE2; Bv[p] = FAKE2; }
  if (lane == 0) Bv[0] = 0x3FFF0400u;  // cell 0 (lo half) on diag 1: w=1024

  // Token queue (parity-packed), all sentinels.
  unsigned q0 = SENT2, q1 = SENT2, q2 = SENT2, q3 = SENT2;

  // Persistent DPP staging register: lane0 = 1024 bias, preserved forever
  // (bound_ctrl=false keeps old dest on lane0; lanes >=1 get overwritten).
  unsigned vseam = BIASHI;

  // Carried shifted-A2 seam: shifted diag-0 (all fake, lane0 lo = 1024).
  unsigned s0c;
  vseam = upd_dpp(vseam, A[3]);
  s0c = __builtin_amdgcn_alignbit(A[3], vseam, 16);

  // ---- Token phase: iterations 0..42 (d = 2..517), double-buffered. ----
#pragma clang loop unroll(disable)
  for (int p = 0; p < 20; ++p) {
    // Body A: prefetch bank B (it=2p+1), consume bank A (it=2p).
#pragma unroll
    for (int j = 0; j < 12; ++j) TLOAD(tB[j]);
    TWAIT12(tA);
    STEPS12(tA);
    // Body B: prefetch bank A (it=2p+2), consume bank B (it=2p+1).
#pragma unroll
    for (int j = 0; j < 12; ++j) TLOAD(tA[j]);
    TWAIT12(tB);
    STEPS12(tB);
  }
  // it=40 in bank A. Load it=41 (tokens 492-503), consume it=40.
#pragma unroll
  for (int j = 0; j < 12; ++j) TLOAD(tB[j]);
  TWAIT12(tA);
  STEPS12(tA);
  // Load it=42: tokens 504-510 advancing, then frozen at 511 (j=7..11;
  // j>=8 inject at d>=514 = provably irrelevant, j=7 needs real 511).
#pragma unroll
  for (int j = 0; j < 7; ++j) TLOAD(tA[j]);
#pragma unroll
  for (int j = 7; j < 12; ++j) TLOADF(tA[j]);
  TWAIT12(tB);
  STEPS12(tB);   // it=41
  TWAIT0(tA);
  STEPS12(tA);   // it=42 (d = 506..517)

  // ---- Load-free phase: iterations 43..84 (d = 518..1021). Token regs
  // hold shifted junk; tokens injected at d>=518 cannot influence the
  // answer (need d+511 <= 1024). Queue keeps shifting real old tokens. ----
#pragma clang loop unroll(disable)
  for (int i = 0; i < 42; ++i) {
    STEPS12(tA);
  }

  // Epilogue: d = 1022, 1023, 1024 (garbage-region injections).
  STEP2(A, Bv, Cv, q0, q1, q2, q3, tA[0], tA[1]);
  STEP1(Cv, A, Bv, q2, q3, q0, q1, tA[2]);

  // Answer: diag 1024 in Bv; cell 511 = lane 63, pair 3, HIGH half.
  // At d = 1024 = BIAS, w = v exactly.
  if (lane == 63) out[b] = (float)(Bv[3] >> 16);
}

extern "C" void kernel_launch(void* const* d_in, const int* in_sizes, int n_in,
                              void* d_out, int out_size, void* d_ws, size_t ws_size,
                              hipStream_t stream) {
  const int* ref = (const int*)d_in[0];
  const int* hyp = (const int*)d_in[1];
  float* out = (float*)d_out;
  edit_distance_kernel<<<BATCH, 64, 0, stream>>>(ref, hyp, out);
}